// Round 1
// baseline (1377.996 us; speedup 1.0000x reference)
//
#include <hip/hip_runtime.h>
#include <hip/hip_bf16.h>

// Problem constants
#define BATCH 16384
#define SEW   2048      // SE == SO == 2048
#define H1W   1024
#define NSTEP 10

typedef unsigned short u16;
typedef __attribute__((ext_vector_type(8))) __bf16 bf16x8;
typedef __attribute__((ext_vector_type(4))) float   f32x4;

// Split fp32 into bf16 hi + bf16 lo (truncation; x == hi + lo + O(2^-16 |x|))
__device__ __forceinline__ void split2(float x, u16& h, u16& l) {
    unsigned u = __float_as_uint(x);
    h = (u16)(u >> 16);
    float hf = __uint_as_float(u & 0xFFFF0000u);
    float r  = x - hf;                       // exact (mantissa suffix)
    l = (u16)(__float_as_uint(r) >> 16);
}

__device__ __forceinline__ float rho_f(float x) {
    return 1.0f / (1.0f + __expf(2.0f - 4.0f * x));
}

// 16-byte async global->LDS copy
__device__ __forceinline__ void gl2lds16(const u16* g, u16* l) {
    __builtin_amdgcn_global_load_lds(
        (const __attribute__((address_space(1))) void*)g,
        (__attribute__((address_space(3))) void*)l, 16, 0, 0);
}

// ---------------------------------------------------------------------------
// prep_w: W (2048x2048 f32) -> Whi/Wlo and transposed WThi/WTlo (bf16 halves)
// ---------------------------------------------------------------------------
__global__ void prep_w(const float* __restrict__ W,
                       u16* __restrict__ Whi, u16* __restrict__ Wlo,
                       u16* __restrict__ WThi, u16* __restrict__ WTlo) {
    __shared__ float tile[32][33];
    const int tx = threadIdx.x, ty = threadIdx.y;
    const int x = blockIdx.x * 32 + tx;
#pragma unroll
    for (int k = 0; k < 4; ++k) {
        int y = blockIdx.y * 32 + ty + k * 8;
        float v = W[y * SEW + x];
        tile[ty + k * 8][tx] = v;
        u16 h, l; split2(v, h, l);
        Whi[y * SEW + x] = h; Wlo[y * SEW + x] = l;
    }
    __syncthreads();
#pragma unroll
    for (int k = 0; k < 4; ++k) {
        int r = blockIdx.x * 32 + ty + k * 8;   // WT row (= W col)
        int c = blockIdx.y * 32 + tx;           // WT col (= W row)
        float v = tile[tx][ty + k * 8];         // = W[c][r]
        u16 h, l; split2(v, h, l);
        WThi[r * SEW + c] = h; WTlo[r * SEW + c] = l;
    }
}

// ---------------------------------------------------------------------------
// prep_rho: R1 = rho(s_even) split to bf16 hi/lo.  s row stride 4096.
// ---------------------------------------------------------------------------
__global__ void prep_rho(const float* __restrict__ s,
                         u16* __restrict__ Rhi, u16* __restrict__ Rlo) {
    int i = blockIdx.x * blockDim.x + threadIdx.x;   // 0 .. B*SE/4-1
    int e = i << 2;
    int row = e >> 11;
    int col = e & 2047;
    const float4 v = *(const float4*)(s + ((size_t)row << 12) + col);
    float xs[4] = {v.x, v.y, v.z, v.w};
    u16 h[4], l[4];
#pragma unroll
    for (int k = 0; k < 4; ++k) {
        float r = rho_f(xs[k]);
        split2(r, h[k], l[k]);
    }
    *(ushort4*)(Rhi + e) = make_ushort4(h[0], h[1], h[2], h[3]);
    *(ushort4*)(Rlo + e) = make_ushort4(l[0], l[1], l[2], l[3]);
}

// ---------------------------------------------------------------------------
// Fused split-bf16 GEMM (128x128 tile, BK=32, 4 waves, 64x64/wave, 4x4 frags)
//  C = A @ B, A: [16384][2048] (hi/lo), B passed TRANSPOSED as BT [N][K] (hi/lo)
//  PHASE 1: C_odd + b_odd (+Ux on cols<1024), iterate s_odd, write out + R2
//  PHASE 2: C_even + b_even, iterate s_even, write out
// ---------------------------------------------------------------------------
template <int PHASE>
__global__ __launch_bounds__(256, 2)
void gemm_fused(const u16* __restrict__ Ahi, const u16* __restrict__ Alo,
                const u16* __restrict__ Bhi, const u16* __restrict__ Blo,
                const float* __restrict__ bias,
                const float* __restrict__ Ux,
                const float* __restrict__ s_in,   // pre-offset, row stride 4096
                float* __restrict__ out,          // pre-offset, row stride 4096
                u16* __restrict__ R2hi, u16* __restrict__ R2lo) {
    __shared__ u16 lsAh[128 * 32], lsAl[128 * 32], lsBh[128 * 32], lsBl[128 * 32];

    const int tid = threadIdx.x;
    const int m0 = blockIdx.x * 128;
    const int n0 = blockIdx.y * 128;

    int k0, k1;
    if (PHASE == 1) { k0 = 0;                      k1 = (n0 < 1024) ? 1024 : 2048; }
    else            { k0 = (n0 < 1024) ? 0 : 1024; k1 = 2048; }

    // --- staging decomposition: 512 16B chunks per tile, 2 per thread ---
    // chunk p -> LDS bytes [p*16, p*16+16) == tile (row=p>>2, slot=p&3)
    // read side XOR-swizzles slot by ((row>>1)&3), so stage the inverse.
    const int p0 = tid, p1 = tid + 256;
    const int r0 = p0 >> 2, r1 = p1 >> 2;
    const int g0 = (p0 & 3) ^ ((r0 >> 1) & 3);
    const int g1 = (p1 & 3) ^ ((r1 >> 1) & 3);
    const int aoff0 = (m0 + r0) * SEW + g0 * 8;
    const int aoff1 = (m0 + r1) * SEW + g1 * 8;
    const int boff0 = (n0 + r0) * SEW + g0 * 8;
    const int boff1 = (n0 + r1) * SEW + g1 * 8;

    // --- fragment read offsets (bytes), swizzled ---
    const int lane = tid & 63;
    const int w = tid >> 6;
    const int wr = w >> 1, wc = w & 1;
    const int q = lane >> 4, lr = lane & 15;
    int offA[4], offB[4];
#pragma unroll
    for (int i = 0; i < 4; ++i) {
        int row = wr * 64 + i * 16 + lr;
        offA[i] = row * 64 + ((q ^ ((row >> 1) & 3)) << 4);
        row = wc * 64 + i * 16 + lr;
        offB[i] = row * 64 + ((q ^ ((row >> 1) & 3)) << 4);
    }

    f32x4 acc[4][4];
    const f32x4 zero = {0.f, 0.f, 0.f, 0.f};
#pragma unroll
    for (int i = 0; i < 4; ++i)
#pragma unroll
        for (int j = 0; j < 4; ++j) acc[i][j] = zero;

    const int nk = (k1 - k0) >> 5;
    for (int kt = 0; kt < nk; ++kt) {
        const int kb = k0 + (kt << 5);
        __syncthreads();   // previous compute done; LDS reusable
        gl2lds16(Ahi + aoff0 + kb, lsAh + p0 * 8);
        gl2lds16(Ahi + aoff1 + kb, lsAh + p1 * 8);
        gl2lds16(Alo + aoff0 + kb, lsAl + p0 * 8);
        gl2lds16(Alo + aoff1 + kb, lsAl + p1 * 8);
        gl2lds16(Bhi + boff0 + kb, lsBh + p0 * 8);
        gl2lds16(Bhi + boff1 + kb, lsBh + p1 * 8);
        gl2lds16(Blo + boff0 + kb, lsBl + p0 * 8);
        gl2lds16(Blo + boff1 + kb, lsBl + p1 * 8);
        __syncthreads();   // vmcnt(0) drain + barrier: tiles ready

        bf16x8 ah[4], al[4], bh[4], bl[4];
#pragma unroll
        for (int i = 0; i < 4; ++i) {
            ah[i] = *(const bf16x8*)((const char*)lsAh + offA[i]);
            al[i] = *(const bf16x8*)((const char*)lsAl + offA[i]);
            bh[i] = *(const bf16x8*)((const char*)lsBh + offB[i]);
            bl[i] = *(const bf16x8*)((const char*)lsBl + offB[i]);
        }
#pragma unroll
        for (int i = 0; i < 4; ++i)
#pragma unroll
            for (int j = 0; j < 4; ++j) {
                acc[i][j] = __builtin_amdgcn_mfma_f32_16x16x32_bf16(ah[i], bh[j], acc[i][j], 0, 0, 0);
                acc[i][j] = __builtin_amdgcn_mfma_f32_16x16x32_bf16(ah[i], bl[j], acc[i][j], 0, 0, 0);
                acc[i][j] = __builtin_amdgcn_mfma_f32_16x16x32_bf16(al[i], bh[j], acc[i][j], 0, 0, 0);
            }
    }

    // --- epilogue: bias (+Ux), 10-step fixed point, stores ---
#pragma unroll
    for (int i = 0; i < 4; ++i) {
#pragma unroll
        for (int j = 0; j < 4; ++j) {
            const int col = n0 + wc * 64 + j * 16 + lr;
            const float bv = bias[col];
            float c[4], sv[4];
#pragma unroll
            for (int jj = 0; jj < 4; ++jj) {
                const int row = m0 + wr * 64 + i * 16 + q * 4 + jj;
                c[jj] = acc[i][j][jj] + bv;
                if (PHASE == 1) {
                    if (n0 < 1024) c[jj] += Ux[(size_t)row * H1W + col];
                }
                sv[jj] = s_in[(size_t)row * 4096 + col];
            }
#pragma unroll 1
            for (int t = 0; t < NSTEP; ++t) {
#pragma unroll
                for (int jj = 0; jj < 4; ++jj) {
                    float r  = rho_f(sv[jj]);
                    float rd = 4.0f * r * (1.0f - r);
                    sv[jj] = 0.5f * sv[jj] + 0.5f * rd * c[jj];
                }
            }
#pragma unroll
            for (int jj = 0; jj < 4; ++jj) {
                const int row = m0 + wr * 64 + i * 16 + q * 4 + jj;
                out[(size_t)row * 4096 + col] = sv[jj];
                if (PHASE == 1) {
                    float r = rho_f(sv[jj]);
                    u16 h, l; split2(r, h, l);
                    R2hi[row * SEW + col] = h;
                    R2lo[row * SEW + col] = l;
                }
            }
        }
    }
}

// ---------------------------------------------------------------------------
extern "C" void kernel_launch(void* const* d_in, const int* in_sizes, int n_in,
                              void* d_out, int out_size, void* d_ws, size_t ws_size,
                              hipStream_t stream) {
    (void)in_sizes; (void)n_in; (void)out_size; (void)ws_size;
    const float* Ux     = (const float*)d_in[0];
    const float* s      = (const float*)d_in[1];
    const float* W      = (const float*)d_in[2];
    const float* b_even = (const float*)d_in[3];
    const float* b_odd  = (const float*)d_in[4];
    float* out = (float*)d_out;

    char* ws = (char*)d_ws;
    const size_t MB = 1024ull * 1024ull;
    // workspace layout (288 MB total)
    u16* R1hi = (u16*)(ws);              // 64 MB  rho(s_even) hi
    u16* R1lo = (u16*)(ws + 64 * MB);    // 64 MB  rho(s_even) lo
    u16* R2hi = (u16*)(ws + 128 * MB);   // 64 MB  rho(s_odd)  hi
    u16* R2lo = (u16*)(ws + 192 * MB);   // 64 MB  rho(s_odd)  lo
    u16* Whi  = (u16*)(ws + 256 * MB);   // 8 MB
    u16* Wlo  = (u16*)(ws + 264 * MB);   // 8 MB
    u16* WThi = (u16*)(ws + 272 * MB);   // 8 MB
    u16* WTlo = (u16*)(ws + 280 * MB);   // 8 MB

    prep_w<<<dim3(64, 64), dim3(32, 8), 0, stream>>>(W, Whi, Wlo, WThi, WTlo);
    prep_rho<<<(BATCH * SEW / 4) / 256, 256, 0, stream>>>(s, R1hi, R1lo);

    // Phase 1: C_odd = rho(s_even) @ W  (BT = WT arrays); iterate s_odd
    gemm_fused<1><<<dim3(128, 16), 256, 0, stream>>>(
        R1hi, R1lo, WThi, WTlo, b_odd, Ux,
        s + SEW, out + SEW, R2hi, R2lo);

    // Phase 2: C_even = rho(s_odd) @ W.T (BT = W arrays); iterate s_even
    gemm_fused<2><<<dim3(128, 16), 256, 0, stream>>>(
        R2hi, R2lo, Whi, Wlo, b_even, nullptr,
        s, out, nullptr, nullptr);
}